// Round 6
// baseline (42.056 us; speedup 1.0000x reference)
//
#include <hip/hip_runtime.h>

#define NB 2
#define NT 4
#define NN 4096
#define NBT (NB*NT)
#define TOTAL (NBT*NN)        // 32768 points per tensor
#define BIGF 1e10f
#define THRESHF 1e9f
#define NEGF (-1e10f)

typedef __attribute__((ext_vector_type(8)))  short s16x8;
typedef __attribute__((ext_vector_type(16))) float f32x16;

// round-to-nearest-even f32 -> bf16 (raw bits)
__device__ inline unsigned short f2bf(float f) {
    unsigned u = __float_as_uint(f);
    u += 0x7fffu + ((u >> 16) & 1u);
    return (unsigned short)(u >> 16);
}
// split x into bf16 hi + bf16 lo (lo = rn(x - hi)); hi+lo represents x to ~2^-17 rel
__device__ inline void split2(float x, unsigned short& hi, unsigned short& lo) {
    hi = f2bf(x);
    float fh = __uint_as_float(((unsigned)hi) << 16);
    lo = f2bf(x - fh);
}
__device__ inline s16x8 mk8(unsigned short a, unsigned short b, unsigned short c, unsigned short d,
                            unsigned short e, unsigned short f, unsigned short g, unsigned short h) {
    return (s16x8){(short)a,(short)b,(short)c,(short)d,(short)e,(short)f,(short)g,(short)h};
}

// Synthetic K=13 (slots 13..15 zero) on mfma_f32_32x32x16_bf16.
// Row point p (split pa+pb), col point t (u = -2t split ua+ub), wp=||p||^2, wt=||t||^2+bias:
//   row k0-7 : pax,pay,paz,pbx,pby,pbz,pax,pay   row k8-15: paz,one,one,wph,wpl,0,0,0
//   col k0-7 : uax,uay,uaz,uax,uay,uaz,ubx,uby   col k8-15: ubz,wth,wtl,one,one,0,0,0
// => D[r,c] = pa·ua + pb·ua + pa·ub + wp + wt = wp + wt - 2 p·t  (err ~4e-6·|p||t|, lo·lo dropped)
// A-frag: lane l -> row l&31, k-chunk l>>5. B-frag: lane l -> col l&31, k-chunk l>>5.
// (A consistent swap of both chunk maps leaves the K-sum invariant.)
// C/D: col = lane&31, row = (reg&3) + 8*(reg>>2) + 4*(lane>>5)  [guide m74/m101, HW-verified]

__global__ __launch_bounds__(256) void prep_kernel(
    const float* __restrict__ pred, const float* __restrict__ targ,
    const int* __restrict__ ic, const int* __restrict__ pad, const int* __restrict__ vis,
    s16x8* __restrict__ rowP, s16x8* __restrict__ rowT,
    s16x8* __restrict__ colP, s16x8* __restrict__ colT,
    unsigned* __restrict__ minp, unsigned* __restrict__ mint,
    float* __restrict__ out)
{
    int i = blockIdx.x * 256 + threadIdx.x;
    if (i == 0) out[0] = 0.0f;              // zero output each call (poison-safe)
    if (i >= TOTAL) return;
    int bt = i >> 12;
    int n  = i & (NN - 1);
    int b  = bt >> 2;
    bool m = (ic[b*NN + n] == 0) && (pad[b*NN + n] != 0) && (vis[i] != 0);
    float bias = m ? 0.0f : BIGF;
    const unsigned short one = 0x3F80;
    int crec = bt*8192 + (n >> 5)*64 + (n & 31);   // 128 tiles/bt, 64 records/tile

    {   // pred: rows for dir=0, cols for dir=1
        float x = pred[3*i], y = pred[3*i+1], z = pred[3*i+2];
        unsigned short ax,ay,az,bx,by,bz,wh,wl, ux,uy,uz,vx,vy,vz,ch,cl;
        split2(x,ax,bx); split2(y,ay,by); split2(z,az,bz);
        float w = fmaf(x,x, fmaf(y,y, z*z));
        split2(w, wh, wl);
        split2(-2.0f*x,ux,vx); split2(-2.0f*y,uy,vy); split2(-2.0f*z,uz,vz);
        split2(w + bias, ch, cl);
        rowP[i]          = mk8(ax,ay,az,bx,by,bz,ax,ay);
        rowP[TOTAL + i]  = mk8(az,one,one,wh,wl,0,0,0);
        colP[crec]       = mk8(ux,uy,uz,ux,uy,uz,vx,vy);
        colP[crec + 32]  = mk8(vz,ch,cl,one,one,0,0,0);
    }
    {   // targ
        float x = targ[3*i], y = targ[3*i+1], z = targ[3*i+2];
        unsigned short ax,ay,az,bx,by,bz,wh,wl, ux,uy,uz,vx,vy,vz,ch,cl;
        split2(x,ax,bx); split2(y,ay,by); split2(z,az,bz);
        float w = fmaf(x,x, fmaf(y,y, z*z));
        split2(w, wh, wl);
        split2(-2.0f*x,ux,vx); split2(-2.0f*y,uy,vy); split2(-2.0f*z,uz,vz);
        split2(w + bias, ch, cl);
        rowT[i]          = mk8(ax,ay,az,bx,by,bz,ax,ay);
        rowT[TOTAL + i]  = mk8(az,one,one,wh,wl,0,0,0);
        colT[crec]       = mk8(ux,uy,uz,ux,uy,uz,vx,vy);
        colT[crec + 32]  = mk8(vz,ch,cl,one,one,0,0,0);
    }

    minp[i] = __float_as_uint(BIGF);
    mint[i] = __float_as_uint(BIGF);
}

// grid (4 colChunks, 8 rowChunks, 16 bt*dir), block 256 = 4 waves.
// Wave owns 128 rows (4 x 32-row tiles); block stages 1024 cols = 32 col-tiles (32 KB LDS).
__global__ __launch_bounds__(256, 2) void min_kernel(
    const s16x8* __restrict__ rowP, const s16x8* __restrict__ rowT,
    const s16x8* __restrict__ colP, const s16x8* __restrict__ colT,
    unsigned* __restrict__ minp, unsigned* __restrict__ mint)
{
    __shared__ s16x8 ldsB[2048];   // 32 KB
    const int tid  = threadIdx.x;
    const int lane = tid & 63;
    const int w    = tid >> 6;
    const int cc   = blockIdx.x;
    const int rc   = blockIdx.y;
    const int z    = blockIdx.z;
    const int bt   = z >> 1;
    const int dir  = z & 1;
    const s16x8* __restrict__ rowf = dir ? rowT : rowP;
    const s16x8* __restrict__ colf = dir ? colP : colT;
    unsigned* outp = dir ? mint : minp;

    // stage 32 col-tiles (2048 records of 16B)
    const s16x8* src = colf + bt*8192 + cc*2048;
    #pragma unroll
    for (int it = 0; it < 8; ++it)
        ldsB[it*256 + tid] = src[it*256 + tid];
    __syncthreads();

    const int h = lane >> 5;        // k-chunk 0/1
    const int c = lane & 31;        // row/col within tile
    const int n0 = rc*512 + w*128;

    f32x16 zf;
    s16x8 a[4];
    f32x16 mm[4];
    #pragma unroll
    for (int q = 0; q < 16; ++q) zf[q] = 0.0f;
    #pragma unroll
    for (int rt = 0; rt < 4; ++rt) {
        a[rt] = rowf[h*TOTAL + bt*NN + n0 + rt*32 + c];
        #pragma unroll
        for (int q = 0; q < 16; ++q) mm[rt][q] = 3.4e38f;
    }

    #pragma unroll 1
    for (int tp = 0; tp < 16; ++tp) {
        s16x8 b0 = ldsB[tp*128 + lane];
        s16x8 b1 = ldsB[tp*128 + 64 + lane];
        #pragma unroll
        for (int rt = 0; rt < 4; ++rt) {
            f32x16 D0 = __builtin_amdgcn_mfma_f32_32x32x16_bf16(a[rt], b0, zf, 0, 0, 0);
            f32x16 D1 = __builtin_amdgcn_mfma_f32_32x32x16_bf16(a[rt], b1, zf, 0, 0, 0);
            #pragma unroll
            for (int q = 0; q < 16; ++q)
                mm[rt][q] = fminf(fminf(D0[q], D1[q]), mm[rt][q]);   // v_min3
        }
    }

    // butterfly min across the 32 columns (within each 32-lane half)
    #pragma unroll
    for (int off = 1; off <= 16; off <<= 1) {
        #pragma unroll
        for (int rt = 0; rt < 4; ++rt) {
            #pragma unroll
            for (int q = 0; q < 16; ++q)
                mm[rt][q] = fminf(mm[rt][q], __shfl_xor(mm[rt][q], off));
        }
    }

    // publish: lane c==j (one per half) owns reg j; row = (j&3)+8*(j>>2)+4*h
    #pragma unroll
    for (int j = 0; j < 16; ++j) {
        if (c == j) {
            const int ro = (j & 3) + 8*(j >> 2) + 4*h;
            const int rb = bt*NN + n0 + ro;
            #pragma unroll
            for (int rt = 0; rt < 4; ++rt) {
                float x = mm[rt][j];
                unsigned bits = __float_as_uint(fmaxf(x, 0.0f));
                if (!(x == x))           bits = __float_as_uint(BIGF);  // NaN guard
                if (bits == 0x80000000u) bits = 0u;                     // -0 -> +0
                atomicMin(&outp[rb + rt*32], bits);
            }
        }
    }
}

// one block per (b,t): cd + soft-hausdorff, atomicAdd contribution into out[0]
__global__ __launch_bounds__(256) void finalize_kernel(
    const unsigned* __restrict__ minp, const unsigned* __restrict__ mint,
    const int* __restrict__ ic, const int* __restrict__ pad, const int* __restrict__ vis,
    float* __restrict__ out)
{
    const int bt = blockIdx.x;
    const int b  = bt >> 2;
    const int tid = threadIdx.x;

    float hp[16], ht[16];
    float nv = 0.f, scdp = 0.f, scdt = 0.f, mhp = NEGF, mht = NEGF;
    #pragma unroll
    for (int k = 0; k < 16; ++k) {
        int n  = tid + k*256;
        int gi = bt*NN + n;
        bool m = (ic[b*NN + n] == 0) && (pad[b*NN + n] != 0) && (vis[gi] != 0);
        float mp = __uint_as_float(minp[gi]);
        float mt = __uint_as_float(mint[gi]);
        if (!(mp <= 2e10f)) mp = BIGF;   // NaN/garbage guard (legit values <= ~1.1e10)
        if (!(mt <= 2e10f)) mt = BIGF;
        float hpv = m ? fminf(mp, THRESHF) : NEGF;
        float htv = m ? fminf(mt, THRESHF) : NEGF;
        hp[k] = hpv; ht[k] = htv;
        if (m) {
            nv += 1.f;
            scdp += (mp > THRESHF) ? 0.f : mp;
            scdt += (mt > THRESHF) ? 0.f : mt;
            mhp = fmaxf(mhp, hpv);
            mht = fmaxf(mht, htv);
        }
    }

    __shared__ float red[4][5];
    const int wid = tid >> 6;
    #pragma unroll
    for (int o = 32; o > 0; o >>= 1) {
        nv   += __shfl_xor(nv, o);
        scdp += __shfl_xor(scdp, o);
        scdt += __shfl_xor(scdt, o);
        mhp   = fmaxf(mhp, __shfl_xor(mhp, o));
        mht   = fmaxf(mht, __shfl_xor(mht, o));
    }
    if ((tid & 63) == 0) {
        red[wid][0] = nv; red[wid][1] = scdp; red[wid][2] = scdt;
        red[wid][3] = mhp; red[wid][4] = mht;
    }
    __syncthreads();
    nv   = red[0][0] + red[1][0] + red[2][0] + red[3][0];
    scdp = red[0][1] + red[1][1] + red[2][1] + red[3][1];
    scdt = red[0][2] + red[1][2] + red[2][2] + red[3][2];
    mhp  = fmaxf(fmaxf(red[0][3], red[1][3]), fmaxf(red[2][3], red[3][3]));
    mht  = fmaxf(fmaxf(red[0][4], red[1][4]), fmaxf(red[2][4], red[3][4]));
    __syncthreads();

    float Zp = 0.f, Sp = 0.f, Zt = 0.f, St = 0.f;
    #pragma unroll
    for (int k = 0; k < 16; ++k) {
        float hpv = hp[k];
        if (hpv > -THRESHF) { float e = __expf((hpv - mhp) * 10.0f); Zp += e; Sp += hpv * e; }
        float htv = ht[k];
        if (htv > -THRESHF) { float e = __expf((htv - mht) * 10.0f); Zt += e; St += htv * e; }
    }
    #pragma unroll
    for (int o = 32; o > 0; o >>= 1) {
        Zp += __shfl_xor(Zp, o);
        Sp += __shfl_xor(Sp, o);
        Zt += __shfl_xor(Zt, o);
        St += __shfl_xor(St, o);
    }
    if ((tid & 63) == 0) {
        red[wid][0] = Zp; red[wid][1] = Sp; red[wid][2] = Zt; red[wid][3] = St;
    }
    __syncthreads();
    if (tid == 0) {
        Zp = red[0][0] + red[1][0] + red[2][0] + red[3][0];
        Sp = red[0][1] + red[1][1] + red[2][1] + red[3][1];
        Zt = red[0][2] + red[1][2] + red[2][2] + red[3][2];
        St = red[0][3] + red[1][3] + red[2][3] + red[3][3];
        float nvm = fmaxf(nv, 1.f);
        float cd  = scdp / nvm + scdt / nvm;
        float sp  = (nv > 0.f) ? (Sp / Zp) : 0.f;
        float st  = (nv > 0.f) ? (St / Zt) : 0.f;
        float hd  = fmaxf(sp, st);
        atomicAdd(out, (0.5f * cd + 0.5f * hd) * 0.125f);
    }
}

extern "C" void kernel_launch(void* const* d_in, const int* in_sizes, int n_in,
                              void* d_out, int out_size, void* d_ws, size_t ws_size,
                              hipStream_t stream)
{
    const float* pred = (const float*)d_in[0];
    const float* targ = (const float*)d_in[1];
    const int*   ic   = (const int*)d_in[2];
    const int*   pad  = (const int*)d_in[3];
    const int*   vis  = (const int*)d_in[4];
    float* out = (float*)d_out;

    char* ws = (char*)d_ws;
    s16x8* rowP = (s16x8*)ws;
    s16x8* rowT = rowP + 2*TOTAL;
    s16x8* colP = rowT + 2*TOTAL;
    s16x8* colT = colP + 2*TOTAL;
    unsigned* minp = (unsigned*)(colT + 2*TOTAL);
    unsigned* mint = minp + TOTAL;

    prep_kernel<<<TOTAL/256, 256, 0, stream>>>(pred, targ, ic, pad, vis,
                                               rowP, rowT, colP, colT, minp, mint, out);
    dim3 grid(4, 8, 16);
    min_kernel<<<grid, 256, 0, stream>>>(rowP, rowT, colP, colT, minp, mint);
    finalize_kernel<<<NBT, 256, 0, stream>>>(minp, mint, ic, pad, vis, out);
}

// Round 7
// 27.118 us; speedup vs baseline: 1.5509x; 1.5509x over previous
//
#include <hip/hip_runtime.h>

#define NB 2
#define NT 4
#define NN 4096
#define NBT (NB*NT)
#define TOTAL (NBT*NN)        // 32768 points per tensor
#define BIGF 1e10f
#define THRESHF 1e9f
#define NEGF (-1e10f)

typedef __attribute__((ext_vector_type(8)))  short s16x8;
typedef __attribute__((ext_vector_type(16))) float f32x16;

// round-to-nearest-even f32 -> bf16 (raw bits)
__device__ inline unsigned short f2bf(float f) {
    unsigned u = __float_as_uint(f);
    u += 0x7fffu + ((u >> 16) & 1u);
    return (unsigned short)(u >> 16);
}
// split x into bf16 hi + bf16 lo (lo = rn(x - hi)); hi+lo represents x to ~2^-17 rel
__device__ inline void split2(float x, unsigned short& hi, unsigned short& lo) {
    hi = f2bf(x);
    float fh = __uint_as_float(((unsigned)hi) << 16);
    lo = f2bf(x - fh);
}
__device__ inline s16x8 mk8(unsigned short a, unsigned short b, unsigned short c, unsigned short d,
                            unsigned short e, unsigned short f, unsigned short g, unsigned short h) {
    return (s16x8){(short)a,(short)b,(short)c,(short)d,(short)e,(short)f,(short)g,(short)h};
}

// Synthetic K=13 (slots 13..15 zero) on mfma_f32_32x32x16_bf16 (round-6 verified, absmax 0.0).
// Row point p (split pa+pb), col point t (u = -2t split ua+ub), wp=||p||^2, wt=||t||^2+bias:
//   row chunk0: pax,pay,paz,pbx,pby,pbz,pax,pay   chunk1: paz,one,one,wph,wpl,0,0,0
//   col chunk0: uax,uay,uaz,uax,uay,uaz,ubx,uby   chunk1: ubz,wth,wtl,one,one,0,0,0
// => D[r,c] = wp + wt - 2 p.t  (lo*lo term dropped, err ~4e-6)
// A/B frag: lane l -> row/col l&31, k-chunk l>>5.
// C/D: col = lane&31, row = (reg&3) + 8*(reg>>2) + 4*(lane>>5)

// Fused kernel: computes col packs in LDS from raw floats, row packs in regs,
// then MFMA row-min over its 2048-col half. Plain stores to per-cc partial buffers.
// grid (2 cc, 16 rc, 16 bt*dir), block 256 = 4 waves; 64 KB LDS; 2 blocks/CU.
__global__ __launch_bounds__(256, 2) void min_kernel(
    const float* __restrict__ pred, const float* __restrict__ targ,
    const int* __restrict__ ic, const int* __restrict__ pad, const int* __restrict__ vis,
    unsigned* __restrict__ minp, unsigned* __restrict__ mint,
    float* __restrict__ out)
{
    __shared__ s16x8 ldsB[4096];   // 64 tiles x 64 records x 16B = 64 KB
    const int tid  = threadIdx.x;
    const int lane = tid & 63;
    const int w    = tid >> 6;
    const int cc   = blockIdx.x;
    const int rc   = blockIdx.y;
    const int z    = blockIdx.z;
    const int bt   = z >> 1;
    const int dir  = z & 1;
    const int b    = bt >> 2;
    if (cc == 0 && rc == 0 && z == 0 && tid == 0) out[0] = 0.0f;  // poison-safe zero

    const float* __restrict__ rowraw = dir ? targ : pred;
    const float* __restrict__ colraw = dir ? pred : targ;
    unsigned* outp = (dir ? mint : minp) + cc * TOTAL;
    const unsigned short one = 0x3F80;

    // ---- stage 2048 column packs into LDS (computed from raw floats + mask) ----
    #pragma unroll
    for (int r = 0; r < 8; ++r) {
        int nloc = r*256 + tid;                 // local col 0..2047
        int n    = cc*2048 + nloc;              // col within bt
        int gi   = bt*NN + n;
        bool m = (ic[b*NN + n] == 0) && (pad[b*NN + n] != 0) && (vis[gi] != 0);
        float bias = m ? 0.0f : BIGF;
        float x = colraw[3*gi], y = colraw[3*gi+1], zc = colraw[3*gi+2];
        unsigned short ux,uy,uz,vx,vy,vz,ch,cl;
        split2(-2.0f*x,ux,vx); split2(-2.0f*y,uy,vy); split2(-2.0f*zc,uz,vz);
        float wn = fmaf(x,x, fmaf(y,y, zc*zc));
        split2(wn + bias, ch, cl);
        int tile = nloc >> 5;
        int c32  = tid & 31;                    // == nloc & 31
        ldsB[tile*64 + c32]      = mk8(ux,uy,uz,ux,uy,uz,vx,vy);
        ldsB[tile*64 + 32 + c32] = mk8(vz,ch,cl,one,one,0,0,0);
    }

    // ---- row fragments in registers (2 x 32-row tiles per wave) ----
    const int h  = lane >> 5;       // k-chunk
    const int c  = lane & 31;       // row within tile
    const int n0 = rc*256 + w*64;
    s16x8 a[2];
    #pragma unroll
    for (int rt = 0; rt < 2; ++rt) {
        int row = bt*NN + n0 + rt*32 + c;
        float x = rowraw[3*row], y = rowraw[3*row+1], zc = rowraw[3*row+2];
        unsigned short ax,ay,az,bx,by,bz,wh,wl;
        split2(x,ax,bx); split2(y,ay,by); split2(zc,az,bz);
        float wn = fmaf(x,x, fmaf(y,y, zc*zc));
        split2(wn, wh, wl);
        a[rt] = h ? mk8(az,one,one,wh,wl,0,0,0) : mk8(ax,ay,az,bx,by,bz,ax,ay);
    }

    __syncthreads();

    f32x16 zf, mm[2];
    #pragma unroll
    for (int q = 0; q < 16; ++q) { zf[q] = 0.0f; mm[0][q] = 3.4e38f; mm[1][q] = 3.4e38f; }

    #pragma unroll 1
    for (int tp = 0; tp < 32; ++tp) {
        s16x8 b0 = ldsB[tp*128 + lane];
        s16x8 b1 = ldsB[tp*128 + 64 + lane];
        #pragma unroll
        for (int rt = 0; rt < 2; ++rt) {
            f32x16 D0 = __builtin_amdgcn_mfma_f32_32x32x16_bf16(a[rt], b0, zf, 0, 0, 0);
            f32x16 D1 = __builtin_amdgcn_mfma_f32_32x32x16_bf16(a[rt], b1, zf, 0, 0, 0);
            #pragma unroll
            for (int q = 0; q < 16; ++q)
                mm[rt][q] = fminf(fminf(D0[q], D1[q]), mm[rt][q]);   // v_min3
        }
    }

    // butterfly min across the 32 columns (within each 32-lane half)
    #pragma unroll
    for (int off = 1; off <= 16; off <<= 1) {
        #pragma unroll
        for (int rt = 0; rt < 2; ++rt) {
            #pragma unroll
            for (int q = 0; q < 16; ++q)
                mm[rt][q] = fminf(mm[rt][q], __shfl_xor(mm[rt][q], off));
        }
    }

    // publish partial mins: lane c==j (one per half) owns reg j; row = (j&3)+8*(j>>2)+4*h
    #pragma unroll
    for (int j = 0; j < 16; ++j) {
        if (c == j) {
            const int ro = (j & 3) + 8*(j >> 2) + 4*h;
            const int rb = bt*NN + n0 + ro;
            #pragma unroll
            for (int rt = 0; rt < 2; ++rt) {
                float x = mm[rt][j];
                unsigned bits = __float_as_uint(fmaxf(x, 0.0f));
                if (!(x == x))           bits = __float_as_uint(BIGF);  // NaN guard
                if (bits == 0x80000000u) bits = 0u;                     // -0 -> +0
                outp[rb + rt*32] = bits;                                // plain store (slot owned)
            }
        }
    }
}

// one block per (b,t), 1024 threads, 4 elems/thread via uint4/int4 loads.
__global__ __launch_bounds__(1024) void finalize_kernel(
    const unsigned* __restrict__ minp, const unsigned* __restrict__ mint,
    const int* __restrict__ ic, const int* __restrict__ pad, const int* __restrict__ vis,
    float* __restrict__ out)
{
    const int bt  = blockIdx.x;
    const int b   = bt >> 2;
    const int tid = threadIdx.x;

    uint4 p0 = ((const uint4*)(minp + bt*NN))[tid];
    uint4 p1 = ((const uint4*)(minp + TOTAL + bt*NN))[tid];
    uint4 t0 = ((const uint4*)(mint + bt*NN))[tid];
    uint4 t1 = ((const uint4*)(mint + TOTAL + bt*NN))[tid];
    int4 ic4  = ((const int4*)(ic  + b*NN))[tid];
    int4 pad4 = ((const int4*)(pad + b*NN))[tid];
    int4 vis4 = ((const int4*)(vis + bt*NN))[tid];

    unsigned pu[4] = { p0.x < p1.x ? p0.x : p1.x, p0.y < p1.y ? p0.y : p1.y,
                       p0.z < p1.z ? p0.z : p1.z, p0.w < p1.w ? p0.w : p1.w };
    unsigned tu[4] = { t0.x < t1.x ? t0.x : t1.x, t0.y < t1.y ? t0.y : t1.y,
                       t0.z < t1.z ? t0.z : t1.z, t0.w < t1.w ? t0.w : t1.w };
    int icv[4]  = { ic4.x, ic4.y, ic4.z, ic4.w };
    int padv[4] = { pad4.x, pad4.y, pad4.z, pad4.w };
    int visv[4] = { vis4.x, vis4.y, vis4.z, vis4.w };

    float hp[4], ht[4];
    float nv = 0.f, scdp = 0.f, scdt = 0.f, mhp = NEGF, mht = NEGF;
    #pragma unroll
    for (int e = 0; e < 4; ++e) {
        bool m = (icv[e] == 0) && (padv[e] != 0) && (visv[e] != 0);
        float mp = __uint_as_float(pu[e]);
        float mt = __uint_as_float(tu[e]);
        if (!(mp <= 2e10f)) mp = BIGF;   // NaN/garbage guard
        if (!(mt <= 2e10f)) mt = BIGF;
        float hpv = m ? fminf(mp, THRESHF) : NEGF;
        float htv = m ? fminf(mt, THRESHF) : NEGF;
        hp[e] = hpv; ht[e] = htv;
        if (m) {
            nv += 1.f;
            scdp += (mp > THRESHF) ? 0.f : mp;
            scdt += (mt > THRESHF) ? 0.f : mt;
            mhp = fmaxf(mhp, hpv);
            mht = fmaxf(mht, htv);
        }
    }

    __shared__ float red[16][5];
    const int wid = tid >> 6;
    #pragma unroll
    for (int o = 32; o > 0; o >>= 1) {
        nv   += __shfl_xor(nv, o);
        scdp += __shfl_xor(scdp, o);
        scdt += __shfl_xor(scdt, o);
        mhp   = fmaxf(mhp, __shfl_xor(mhp, o));
        mht   = fmaxf(mht, __shfl_xor(mht, o));
    }
    if ((tid & 63) == 0) {
        red[wid][0] = nv; red[wid][1] = scdp; red[wid][2] = scdt;
        red[wid][3] = mhp; red[wid][4] = mht;
    }
    __syncthreads();
    nv = 0.f; scdp = 0.f; scdt = 0.f; mhp = NEGF; mht = NEGF;
    #pragma unroll
    for (int k = 0; k < 16; ++k) {
        nv += red[k][0]; scdp += red[k][1]; scdt += red[k][2];
        mhp = fmaxf(mhp, red[k][3]); mht = fmaxf(mht, red[k][4]);
    }
    __syncthreads();

    float Zp = 0.f, Sp = 0.f, Zt = 0.f, St = 0.f;
    #pragma unroll
    for (int e = 0; e < 4; ++e) {
        float hpv = hp[e];
        if (hpv > -THRESHF) { float x = __expf((hpv - mhp) * 10.0f); Zp += x; Sp += hpv * x; }
        float htv = ht[e];
        if (htv > -THRESHF) { float x = __expf((htv - mht) * 10.0f); Zt += x; St += htv * x; }
    }
    #pragma unroll
    for (int o = 32; o > 0; o >>= 1) {
        Zp += __shfl_xor(Zp, o);
        Sp += __shfl_xor(Sp, o);
        Zt += __shfl_xor(Zt, o);
        St += __shfl_xor(St, o);
    }
    __shared__ float red2[16][4];
    if ((tid & 63) == 0) {
        red2[wid][0] = Zp; red2[wid][1] = Sp; red2[wid][2] = Zt; red2[wid][3] = St;
    }
    __syncthreads();
    if (tid == 0) {
        Zp = 0.f; Sp = 0.f; Zt = 0.f; St = 0.f;
        #pragma unroll
        for (int k = 0; k < 16; ++k) {
            Zp += red2[k][0]; Sp += red2[k][1]; Zt += red2[k][2]; St += red2[k][3];
        }
        float nvm = fmaxf(nv, 1.f);
        float cd  = scdp / nvm + scdt / nvm;
        float sp  = (nv > 0.f) ? (Sp / Zp) : 0.f;
        float st  = (nv > 0.f) ? (St / Zt) : 0.f;
        float hd  = fmaxf(sp, st);
        atomicAdd(out, (0.5f * cd + 0.5f * hd) * 0.125f);
    }
}

extern "C" void kernel_launch(void* const* d_in, const int* in_sizes, int n_in,
                              void* d_out, int out_size, void* d_ws, size_t ws_size,
                              hipStream_t stream)
{
    const float* pred = (const float*)d_in[0];
    const float* targ = (const float*)d_in[1];
    const int*   ic   = (const int*)d_in[2];
    const int*   pad  = (const int*)d_in[3];
    const int*   vis  = (const int*)d_in[4];
    float* out = (float*)d_out;

    unsigned* minp = (unsigned*)d_ws;                 // 2*TOTAL partial mins (cc0, cc1)
    unsigned* mint = minp + 2*TOTAL;                  // 2*TOTAL

    dim3 grid(2, 16, 16);
    min_kernel<<<grid, 256, 0, stream>>>(pred, targ, ic, pad, vis, minp, mint, out);
    finalize_kernel<<<NBT, 1024, 0, stream>>>(minp, mint, ic, pad, vis, out);
}

// Round 8
// 23.560 us; speedup vs baseline: 1.7850x; 1.1510x over previous
//
#include <hip/hip_runtime.h>

#define NB 2
#define NT 4
#define NN 4096
#define NBT (NB*NT)
#define TOTAL (NBT*NN)        // 32768 points per tensor
#define BIGF 1e10f
#define THRESHF 1e9f
#define NEGF (-1e10f)

typedef __attribute__((ext_vector_type(8)))  short s16x8;
typedef __attribute__((ext_vector_type(16))) float f32x16;

// round-to-nearest-even f32 -> bf16 (raw bits)
__device__ inline unsigned short f2bf(float f) {
    unsigned u = __float_as_uint(f);
    u += 0x7fffu + ((u >> 16) & 1u);
    return (unsigned short)(u >> 16);
}
// split x into bf16 hi + bf16 lo (lo = rn(x - hi)); hi+lo represents x to ~2^-17 rel
__device__ inline void split2(float x, unsigned short& hi, unsigned short& lo) {
    hi = f2bf(x);
    float fh = __uint_as_float(((unsigned)hi) << 16);
    lo = f2bf(x - fh);
}
__device__ inline s16x8 mk8(unsigned short a, unsigned short b, unsigned short c, unsigned short d,
                            unsigned short e, unsigned short f, unsigned short g, unsigned short h) {
    return (s16x8){(short)a,(short)b,(short)c,(short)d,(short)e,(short)f,(short)g,(short)h};
}

// Synthetic K=13 (slots 13..15 zero) on mfma_f32_32x32x16_bf16 (verified r6/r7, absmax 0.0).
// Row point p (split pa+pb), col point t (u = -2t split ua+ub), wp=||p||^2, wt=||t||^2+bias:
//   row chunk0: pax,pay,paz,pbx,pby,pbz,pax,pay   chunk1: paz,one,one,wph,wpl,0,0,0
//   col chunk0: uax,uay,uaz,uax,uay,uaz,ubx,uby   chunk1: ubz,wth,wtl,one,one,0,0,0
// => D[r,c] = wp + wt - 2 p.t  (lo*lo term dropped, err ~4e-6)
// A/B frag: lane l -> row/col l&31, k-chunk l>>5.
// C/D: col = lane&31, row = (reg&3) + 8*(reg>>2) + 4*(lane>>5)

// Fused kernel: col packs computed into LDS from raw floats, row packs in regs,
// MFMA row-min over this block's 1024-col quarter, LDS-transpose epilogue,
// plain stores to per-cc partial buffers.
// grid (4 cc, 16 rc, 16 bt*dir), block 256 = 4 waves; ~33 KB LDS; 4 blocks/CU.
__global__ __launch_bounds__(256, 4) void min_kernel(
    const float* __restrict__ pred, const float* __restrict__ targ,
    const int* __restrict__ ic, const int* __restrict__ pad, const int* __restrict__ vis,
    unsigned* __restrict__ minp, unsigned* __restrict__ mint,
    float* __restrict__ out)
{
    // 2048 B-records (32 KB) for staging; reused as 4x64x33 f32 (33792 B) in epilogue
    __shared__ __align__(16) char ldsraw[33792];
    s16x8* ldsB = (s16x8*)ldsraw;

    const int tid  = threadIdx.x;
    const int lane = tid & 63;
    const int w    = tid >> 6;
    const int cc   = blockIdx.x;
    const int rc   = blockIdx.y;
    const int z    = blockIdx.z;
    const int bt   = z >> 1;
    const int dir  = z & 1;
    const int b    = bt >> 2;
    if (cc == 0 && rc == 0 && z == 0 && tid == 0) out[0] = 0.0f;  // poison-safe zero

    const float* __restrict__ rowraw = dir ? targ : pred;
    const float* __restrict__ colraw = dir ? pred : targ;
    unsigned* outp = (dir ? mint : minp) + cc * TOTAL;
    const unsigned short one = 0x3F80;

    // ---- stage 1024 column packs into LDS (computed from raw floats + mask) ----
    #pragma unroll
    for (int r = 0; r < 4; ++r) {
        int nloc = r*256 + tid;                 // local col 0..1023
        int n    = cc*1024 + nloc;              // col within bt
        int gi   = bt*NN + n;
        bool m = (ic[b*NN + n] == 0) && (pad[b*NN + n] != 0) && (vis[gi] != 0);
        float bias = m ? 0.0f : BIGF;
        float x = colraw[3*gi], y = colraw[3*gi+1], zc = colraw[3*gi+2];
        unsigned short ux,uy,uz,vx,vy,vz,ch,cl;
        split2(-2.0f*x,ux,vx); split2(-2.0f*y,uy,vy); split2(-2.0f*zc,uz,vz);
        float wn = fmaf(x,x, fmaf(y,y, zc*zc));
        split2(wn + bias, ch, cl);
        int tile = nloc >> 5;
        int c32  = tid & 31;                    // == nloc & 31
        ldsB[tile*64 + c32]      = mk8(ux,uy,uz,ux,uy,uz,vx,vy);
        ldsB[tile*64 + 32 + c32] = mk8(vz,ch,cl,one,one,0,0,0);
    }

    // ---- row fragments in registers (2 x 32-row tiles per wave) ----
    const int h  = lane >> 5;       // k-chunk
    const int c  = lane & 31;       // row within tile
    const int n0 = rc*256 + w*64;
    s16x8 a[2];
    #pragma unroll
    for (int rt = 0; rt < 2; ++rt) {
        int row = bt*NN + n0 + rt*32 + c;
        float x = rowraw[3*row], y = rowraw[3*row+1], zc = rowraw[3*row+2];
        unsigned short ax,ay,az,bx,by,bz,wh,wl;
        split2(x,ax,bx); split2(y,ay,by); split2(zc,az,bz);
        float wn = fmaf(x,x, fmaf(y,y, zc*zc));
        split2(wn, wh, wl);
        a[rt] = h ? mk8(az,one,one,wh,wl,0,0,0) : mk8(ax,ay,az,bx,by,bz,ax,ay);
    }

    __syncthreads();

    f32x16 zf, mm[2];
    #pragma unroll
    for (int q = 0; q < 16; ++q) { zf[q] = 0.0f; mm[0][q] = 3.4e38f; mm[1][q] = 3.4e38f; }

    #pragma unroll 1
    for (int tp = 0; tp < 16; ++tp) {
        s16x8 b0 = ldsB[tp*128 + lane];
        s16x8 b1 = ldsB[tp*128 + 64 + lane];
        #pragma unroll
        for (int rt = 0; rt < 2; ++rt) {
            f32x16 D0 = __builtin_amdgcn_mfma_f32_32x32x16_bf16(a[rt], b0, zf, 0, 0, 0);
            f32x16 D1 = __builtin_amdgcn_mfma_f32_32x32x16_bf16(a[rt], b1, zf, 0, 0, 0);
            #pragma unroll
            for (int q = 0; q < 16; ++q)
                mm[rt][q] = fminf(fminf(D0[q], D1[q]), mm[rt][q]);   // v_min3
        }
    }

    // ---- LDS-transpose epilogue: wave-private [64 rows][33 stride] f32 region ----
    __syncthreads();                 // everyone done reading staged B
    float* fbuf = (float*)ldsraw;
    const int wbase = w * 2112;      // 64*33
    #pragma unroll
    for (int rt = 0; rt < 2; ++rt) {
        #pragma unroll
        for (int q = 0; q < 16; ++q) {
            int rl = rt*32 + (q & 3) + 8*(q >> 2) + 4*h;   // row-local 0..63
            fbuf[wbase + rl*33 + c] = mm[rt][q];
        }
    }
    // lane l owns row-local l: tree-min its 32 column partials (conflict-free stride 33)
    const float* rowp = fbuf + wbase + lane*33;
    float v = 3.4e38f;
    #pragma unroll
    for (int k = 0; k < 32; ++k) v = fminf(v, rowp[k]);
    float xv = fmaxf(v, 0.0f);
    unsigned bits = __float_as_uint(xv);
    if (!(xv == xv))         bits = __float_as_uint(BIGF);  // NaN guard
    if (bits == 0x80000000u) bits = 0u;                     // -0 -> +0
    outp[bt*NN + n0 + lane] = bits;                         // plain store (slot owned)
}

// one block per (b,t), 1024 threads, 4 elems/thread via uint4/int4 loads; min over 4 cc-partials.
__global__ __launch_bounds__(1024) void finalize_kernel(
    const unsigned* __restrict__ minp, const unsigned* __restrict__ mint,
    const int* __restrict__ ic, const int* __restrict__ pad, const int* __restrict__ vis,
    float* __restrict__ out)
{
    const int bt  = blockIdx.x;
    const int b   = bt >> 2;
    const int tid = threadIdx.x;
    const int S   = TOTAL/4;   // uint4 stride between cc partials

    const uint4* pp = (const uint4*)(minp + bt*NN);
    const uint4* tt = (const uint4*)(mint + bt*NN);
    uint4 p0 = pp[tid], p1 = pp[S + tid], p2 = pp[2*S + tid], p3 = pp[3*S + tid];
    uint4 t0 = tt[tid], t1 = tt[S + tid], t2 = tt[2*S + tid], t3 = tt[3*S + tid];
    int4 ic4  = ((const int4*)(ic  + b*NN))[tid];
    int4 pad4 = ((const int4*)(pad + b*NN))[tid];
    int4 vis4 = ((const int4*)(vis + bt*NN))[tid];

    #define MIN4(a,b,c,d) min(min(a,b), min(c,d))
    unsigned pu[4] = { MIN4(p0.x,p1.x,p2.x,p3.x), MIN4(p0.y,p1.y,p2.y,p3.y),
                       MIN4(p0.z,p1.z,p2.z,p3.z), MIN4(p0.w,p1.w,p2.w,p3.w) };
    unsigned tu[4] = { MIN4(t0.x,t1.x,t2.x,t3.x), MIN4(t0.y,t1.y,t2.y,t3.y),
                       MIN4(t0.z,t1.z,t2.z,t3.z), MIN4(t0.w,t1.w,t2.w,t3.w) };
    #undef MIN4
    int icv[4]  = { ic4.x, ic4.y, ic4.z, ic4.w };
    int padv[4] = { pad4.x, pad4.y, pad4.z, pad4.w };
    int visv[4] = { vis4.x, vis4.y, vis4.z, vis4.w };

    float hp[4], ht[4];
    float nv = 0.f, scdp = 0.f, scdt = 0.f, mhp = NEGF, mht = NEGF;
    #pragma unroll
    for (int e = 0; e < 4; ++e) {
        bool m = (icv[e] == 0) && (padv[e] != 0) && (visv[e] != 0);
        float mp = __uint_as_float(pu[e]);
        float mt = __uint_as_float(tu[e]);
        if (!(mp <= 2e10f)) mp = BIGF;   // NaN/garbage guard
        if (!(mt <= 2e10f)) mt = BIGF;
        float hpv = m ? fminf(mp, THRESHF) : NEGF;
        float htv = m ? fminf(mt, THRESHF) : NEGF;
        hp[e] = hpv; ht[e] = htv;
        if (m) {
            nv += 1.f;
            scdp += (mp > THRESHF) ? 0.f : mp;
            scdt += (mt > THRESHF) ? 0.f : mt;
            mhp = fmaxf(mhp, hpv);
            mht = fmaxf(mht, htv);
        }
    }

    __shared__ float red[16][5];
    const int wid = tid >> 6;
    #pragma unroll
    for (int o = 32; o > 0; o >>= 1) {
        nv   += __shfl_xor(nv, o);
        scdp += __shfl_xor(scdp, o);
        scdt += __shfl_xor(scdt, o);
        mhp   = fmaxf(mhp, __shfl_xor(mhp, o));
        mht   = fmaxf(mht, __shfl_xor(mht, o));
    }
    if ((tid & 63) == 0) {
        red[wid][0] = nv; red[wid][1] = scdp; red[wid][2] = scdt;
        red[wid][3] = mhp; red[wid][4] = mht;
    }
    __syncthreads();
    nv = 0.f; scdp = 0.f; scdt = 0.f; mhp = NEGF; mht = NEGF;
    #pragma unroll
    for (int k = 0; k < 16; ++k) {
        nv += red[k][0]; scdp += red[k][1]; scdt += red[k][2];
        mhp = fmaxf(mhp, red[k][3]); mht = fmaxf(mht, red[k][4]);
    }
    __syncthreads();

    float Zp = 0.f, Sp = 0.f, Zt = 0.f, St = 0.f;
    #pragma unroll
    for (int e = 0; e < 4; ++e) {
        float hpv = hp[e];
        if (hpv > -THRESHF) { float x = __expf((hpv - mhp) * 10.0f); Zp += x; Sp += hpv * x; }
        float htv = ht[e];
        if (htv > -THRESHF) { float x = __expf((htv - mht) * 10.0f); Zt += x; St += htv * x; }
    }
    #pragma unroll
    for (int o = 32; o > 0; o >>= 1) {
        Zp += __shfl_xor(Zp, o);
        Sp += __shfl_xor(Sp, o);
        Zt += __shfl_xor(Zt, o);
        St += __shfl_xor(St, o);
    }
    __shared__ float red2[16][4];
    if ((tid & 63) == 0) {
        red2[wid][0] = Zp; red2[wid][1] = Sp; red2[wid][2] = Zt; red2[wid][3] = St;
    }
    __syncthreads();
    if (tid == 0) {
        Zp = 0.f; Sp = 0.f; Zt = 0.f; St = 0.f;
        #pragma unroll
        for (int k = 0; k < 16; ++k) {
            Zp += red2[k][0]; Sp += red2[k][1]; Zt += red2[k][2]; St += red2[k][3];
        }
        float nvm = fmaxf(nv, 1.f);
        float cd  = scdp / nvm + scdt / nvm;
        float sp  = (nv > 0.f) ? (Sp / Zp) : 0.f;
        float st  = (nv > 0.f) ? (St / Zt) : 0.f;
        float hd  = fmaxf(sp, st);
        atomicAdd(out, (0.5f * cd + 0.5f * hd) * 0.125f);
    }
}

extern "C" void kernel_launch(void* const* d_in, const int* in_sizes, int n_in,
                              void* d_out, int out_size, void* d_ws, size_t ws_size,
                              hipStream_t stream)
{
    const float* pred = (const float*)d_in[0];
    const float* targ = (const float*)d_in[1];
    const int*   ic   = (const int*)d_in[2];
    const int*   pad  = (const int*)d_in[3];
    const int*   vis  = (const int*)d_in[4];
    float* out = (float*)d_out;

    unsigned* minp = (unsigned*)d_ws;                 // 4*TOTAL partial mins (cc0..cc3)
    unsigned* mint = minp + 4*TOTAL;                  // 4*TOTAL

    dim3 grid(4, 16, 16);
    min_kernel<<<grid, 256, 0, stream>>>(pred, targ, ic, pad, vis, minp, mint, out);
    finalize_kernel<<<NBT, 1024, 0, stream>>>(minp, mint, ic, pad, vis, out);
}